// Round 4
// baseline (180.444 us; speedup 1.0000x reference)
//
#include <hip/hip_runtime.h>
#include <math.h>

#define NUM_FREQS   64
#define NUM_BINS    128
#define NUM_QUERIES 32768
#define HEAD_DIM    128
#define EPS         1e-8f

// ---------------------------------------------------------------------------
// Prep 1: pack probe-side constants, transposed to [f][b].
// probe4[f*128+b] = { P_real[b][f], P_imag[b][f], -softplus(w[b][f]), mw[b][f] }
// ---------------------------------------------------------------------------
__global__ void prep_probe(const float* __restrict__ rp,
                           const float* __restrict__ wraw,
                           const float* __restrict__ mw,
                           float4* __restrict__ probe4) {
    int tid = blockIdx.x * blockDim.x + threadIdx.x;   // tid = f*128 + b
    if (tid >= NUM_FREQS * NUM_BINS) return;
    int f = tid >> 7;
    int b = tid & 127;
    float pr = rp[b * HEAD_DIM + f];
    float pi = rp[b * HEAD_DIM + NUM_FREQS + f];
    float w  = wraw[b * NUM_FREQS + f];
    float sp = fmaxf(w, 0.0f) + log1pf(expf(-fabsf(w)));   // stable softplus
    float m  = mw[b * NUM_FREQS + f];
    probe4[tid] = make_float4(pr, pi, -sp, m);
}

// ---------------------------------------------------------------------------
// Prep 2: normalize Q rows; write transposed Qri[f][q] (float2) + Qm[f][q].
// ---------------------------------------------------------------------------
__global__ void prep_q(const float* __restrict__ Q,
                       float2* __restrict__ Qri,
                       float*  __restrict__ Qm) {
    int q = blockIdx.x * blockDim.x + threadIdx.x;
    if (q >= NUM_QUERIES) return;
    const float4* Qrow = reinterpret_cast<const float4*>(Q + (size_t)q * HEAD_DIM);
    float4 buf[32];
    float s = 0.0f;
    #pragma unroll
    for (int i = 0; i < 32; i++) {
        float4 v = Qrow[i];
        buf[i] = v;
        s = fmaf(v.x, v.x, fmaf(v.y, v.y, fmaf(v.z, v.z, fmaf(v.w, v.w, s))));
    }
    float inv = 1.0f / (__builtin_amdgcn_sqrtf(s) + EPS);
    #pragma unroll
    for (int i = 0; i < 16; i++) {
        float4 r  = buf[i];        // dims 4i..4i+3       -> real part
        float4 im = buf[16 + i];   // dims 64+4i..64+4i+3 -> imag part
        float rr[4] = { r.x,  r.y,  r.z,  r.w  };
        float ii[4] = { im.x, im.y, im.z, im.w };
        #pragma unroll
        for (int k = 0; k < 4; k++) {
            float qr = rr[k] * inv;
            float qi = ii[k] * inv;
            float qm = __builtin_amdgcn_sqrtf(fmaf(qr, qr, fmaf(qi, qi, EPS)));
            int f = 4 * i + k;
            Qri[(size_t)f * NUM_QUERIES + q] = make_float2(qr, qi);  // coalesced
            Qm [(size_t)f * NUM_QUERIES + q] = qm;
        }
    }
}

// ---------------------------------------------------------------------------
// Main: hybrid lane split — each wave covers 8 queries x 8 bins (1 output per
// lane), looping f = 0..63. All operands are per-lane vector loads (q-side,
// vmcnt-pipelined) or LDS broadcast reads (probe tile, staged once).
// Block = 256 threads (4 waves, same bin-tile, 32 consecutive queries).
// Grid = 16384 blocks -> 65536 waves -> TLP hides the HBM q-stream latency.
// ---------------------------------------------------------------------------
__global__ __launch_bounds__(256) void main_kernel(
        const float4* __restrict__ probe4,
        const float2* __restrict__ Qri,
        const float*  __restrict__ Qm,
        const float*  __restrict__ bias,
        float*        __restrict__ out) {
    __shared__ float4 plds[NUM_FREQS * 8];   // 8 KB probe tile for this btile

    const int tid = threadIdx.x;

    // Bijective XCD swizzle (16384 % 8 == 0): each XCD gets a contiguous
    // logical chunk; within an XCD, btile varies fastest -> the 16 blocks
    // sharing one q-group's 32 KB stream are adjacent in time on one L2.
    const int NBLK    = (NUM_QUERIES / 32) * 16;         // 16384
    const int logical = (blockIdx.x & 7) * (NBLK / 8) + (blockIdx.x >> 3);
    const int qgroup  = logical >> 4;                    // 0..1023
    const int btile   = logical & 15;                    // 0..15
    const int bb      = btile * 8;

    // Stage probe tile: 64f x 8b float4 = 512 float4s, 2 per thread.
    #pragma unroll
    for (int i = 0; i < 2; i++) {
        int idx = i * 256 + tid;           // 0..511 = f*8 + j
        int f = idx >> 3, j = idx & 7;
        plds[idx] = probe4[f * NUM_BINS + bb + j];
    }
    __syncthreads();

    const int lane = tid & 63;
    const int wave = tid >> 6;
    const int lb   = lane & 7;             // bin within tile
    const int lq   = lane >> 3;            // query within group-of-8
    const int q    = qgroup * 32 + wave * 8 + lq;

    const float2* qp = Qri + q;
    const float*  mp = Qm + q;
    const float4* pl = plds + lb;

    float acc = 0.0f;
    #pragma unroll 4
    for (int f = 0; f < NUM_FREQS; f++) {
        float4 P  = pl[f * 8];                              // ds_read_b128
        float2 qv = qp[(size_t)f * NUM_QUERIES];            // coalesced dwordx2
        float  qm = mp[(size_t)f * NUM_QUERIES];            // coalesced dword
        float er = P.x - qv.x;
        float ei = P.y - qv.y;
        float d  = __builtin_amdgcn_sqrtf(fmaf(er, er, fmaf(ei, ei, EPS)));
        acc = fmaf(d, P.z, fmaf(qm, P.w, acc));
    }

    out[(size_t)q * NUM_BINS + bb + lb] = acc + bias[bb + lb];
}

// ---------------------------------------------------------------------------
// Fallback (only if ws_size is too small): fully self-contained, slower.
// ---------------------------------------------------------------------------
__global__ void fallback_kernel(const float* __restrict__ Q,
                                const float* __restrict__ rp,
                                const float* __restrict__ wraw,
                                const float* __restrict__ mw,
                                const float* __restrict__ bias,
                                float* __restrict__ out) {
    __shared__ float qn[HEAD_DIM];
    __shared__ float qmag[NUM_FREQS];
    __shared__ float red[NUM_BINS];
    const int t = threadIdx.x;
    const int q = blockIdx.x;

    float v = Q[(size_t)q * HEAD_DIM + t];
    red[t] = v * v;
    __syncthreads();
    for (int s = 64; s > 0; s >>= 1) {
        if (t < s) red[t] += red[t + s];
        __syncthreads();
    }
    float inv = 1.0f / (__builtin_amdgcn_sqrtf(red[0]) + EPS);
    qn[t] = v * inv;
    __syncthreads();
    if (t < NUM_FREQS) {
        float a = qn[t], c = qn[t + NUM_FREQS];
        qmag[t] = __builtin_amdgcn_sqrtf(fmaf(a, a, fmaf(c, c, EPS)));
    }
    __syncthreads();

    const int b = t;
    float acc = 0.0f;
    for (int f = 0; f < NUM_FREQS; f++) {
        float pr = rp[(size_t)b * HEAD_DIM + f];
        float pi = rp[(size_t)b * HEAD_DIM + NUM_FREQS + f];
        float w  = wraw[(size_t)b * NUM_FREQS + f];
        float ew = -(fmaxf(w, 0.0f) + log1pf(expf(-fabsf(w))));
        float er = pr - qn[f];
        float ei = pi - qn[f + NUM_FREQS];
        float d  = __builtin_amdgcn_sqrtf(fmaf(er, er, fmaf(ei, ei, EPS)));
        acc = fmaf(d, ew, fmaf(qmag[f], mw[(size_t)b * NUM_FREQS + f], acc));
    }
    out[(size_t)q * NUM_BINS + b] = acc + bias[b];
}

// ---------------------------------------------------------------------------
extern "C" void kernel_launch(void* const* d_in, const int* in_sizes, int n_in,
                              void* d_out, int out_size, void* d_ws, size_t ws_size,
                              hipStream_t stream) {
    const float* Q    = (const float*)d_in[0];
    const float* rp   = (const float*)d_in[1];
    const float* wraw = (const float*)d_in[2];
    const float* mw   = (const float*)d_in[3];
    const float* bias = (const float*)d_in[4];
    float* out = (float*)d_out;

    const size_t probeBytes = (size_t)NUM_FREQS * NUM_BINS * sizeof(float4);    // 128 KiB
    const size_t qriBytes   = (size_t)NUM_FREQS * NUM_QUERIES * sizeof(float2); // 16 MiB
    const size_t qmBytes    = (size_t)NUM_FREQS * NUM_QUERIES * sizeof(float);  //  8 MiB
    const size_t need       = probeBytes + qriBytes + qmBytes;                  // 24.1 MiB

    if (ws_size >= need) {
        float4* probe4 = (float4*)d_ws;
        float2* Qri    = (float2*)((char*)d_ws + probeBytes);
        float*  Qm     = (float*)((char*)d_ws + probeBytes + qriBytes);

        hipLaunchKernelGGL(prep_probe, dim3((NUM_FREQS * NUM_BINS + 255) / 256),
                           dim3(256), 0, stream, rp, wraw, mw, probe4);
        hipLaunchKernelGGL(prep_q, dim3(NUM_QUERIES / 256), dim3(256), 0, stream,
                           Q, Qri, Qm);
        hipLaunchKernelGGL(main_kernel, dim3((NUM_QUERIES / 32) * 16), dim3(256),
                           0, stream, probe4, Qri, Qm, bias, out);
    } else {
        hipLaunchKernelGGL(fallback_kernel, dim3(NUM_QUERIES), dim3(NUM_BINS), 0,
                           stream, Q, rp, wraw, mw, bias, out);
    }
}

// Round 5
// 96.871 us; speedup vs baseline: 1.8627x; 1.8627x over previous
//
#include <hip/hip_runtime.h>
#include <math.h>

#define NUM_FREQS   64
#define NUM_BINS    128
#define NUM_QUERIES 32768
#define HEAD_DIM    128
#define EPS         1e-8f
#define NQ          16   // queries per block in main kernel

// ---------------------------------------------------------------------------
// Prep 1: pack probe-side constants, transposed to [f][b].
// probe4[f*128+b] = { P_real[b][f], P_imag[b][f], -softplus(w[b][f]), mw[b][f] }
// ---------------------------------------------------------------------------
__global__ void prep_probe(const float* __restrict__ rp,
                           const float* __restrict__ wraw,
                           const float* __restrict__ mw,
                           float4* __restrict__ probe4) {
    int tid = blockIdx.x * blockDim.x + threadIdx.x;   // tid = f*128 + b
    if (tid >= NUM_FREQS * NUM_BINS) return;
    int f = tid >> 7;
    int b = tid & 127;
    float pr = rp[b * HEAD_DIM + f];
    float pi = rp[b * HEAD_DIM + NUM_FREQS + f];
    float w  = wraw[b * NUM_FREQS + f];
    float sp = fmaxf(w, 0.0f) + log1pf(expf(-fabsf(w)));   // stable softplus
    float m  = mw[b * NUM_FREQS + f];
    probe4[tid] = make_float4(pr, pi, -sp, m);
}

// ---------------------------------------------------------------------------
// Prep 2: normalize Q rows; write transposed Qri[f][q] (float2) + Qm[f][q].
// ---------------------------------------------------------------------------
__global__ void prep_q(const float* __restrict__ Q,
                       float2* __restrict__ Qri,
                       float*  __restrict__ Qm) {
    int q = blockIdx.x * blockDim.x + threadIdx.x;
    if (q >= NUM_QUERIES) return;
    const float4* Qrow = reinterpret_cast<const float4*>(Q + (size_t)q * HEAD_DIM);
    float4 buf[32];
    float s = 0.0f;
    #pragma unroll
    for (int i = 0; i < 32; i++) {
        float4 v = Qrow[i];
        buf[i] = v;
        s = fmaf(v.x, v.x, fmaf(v.y, v.y, fmaf(v.z, v.z, fmaf(v.w, v.w, s))));
    }
    float inv = 1.0f / (__builtin_amdgcn_sqrtf(s) + EPS);
    #pragma unroll
    for (int i = 0; i < 16; i++) {
        float4 r  = buf[i];        // dims 4i..4i+3       -> real part
        float4 im = buf[16 + i];   // dims 64+4i..64+4i+3 -> imag part
        float rr[4] = { r.x,  r.y,  r.z,  r.w  };
        float ii[4] = { im.x, im.y, im.z, im.w };
        #pragma unroll
        for (int k = 0; k < 4; k++) {
            float qr = rr[k] * inv;
            float qi = ii[k] * inv;
            float qm = __builtin_amdgcn_sqrtf(fmaf(qr, qr, fmaf(qi, qi, EPS)));
            int f = 4 * i + k;
            Qri[(size_t)f * NUM_QUERIES + q] = make_float2(qr, qi);  // coalesced
            Qm [(size_t)f * NUM_QUERIES + q] = qm;
        }
    }
}

// ---------------------------------------------------------------------------
// Main: block = 128 threads (one per bin), NQ=16 queries per block.
// q-panel (16 KB) staged into LDS once; inner loop reads it via ds_read_b128
// BROADCAST (uniform address -> conflict-free, in-order lgkm -> pipelinable).
// Probe side: one coalesced float4 global load per f, depth-1 prefetched.
// All per-iteration operands now come from in-order, prefetchable pipes.
// ---------------------------------------------------------------------------
__global__ __launch_bounds__(128) void main_kernel(
        const float4* __restrict__ probe4,
        const float2* __restrict__ Qri,
        const float*  __restrict__ Qm,
        const float*  __restrict__ bias,
        float*        __restrict__ out) {
    __shared__ float4 qlds[NUM_FREQS * NQ];   // 16 KB: {qr, qi, qm, 0} per (f,j)

    const int b     = threadIdx.x;
    const int qbase = blockIdx.x * NQ;

    // Stage q-panel: 1024 float4 entries, 8 per thread. Reads are coalesced in
    // 128 B segments (16 consecutive float2 / float per f-row).
    #pragma unroll
    for (int i = 0; i < (NUM_FREQS * NQ) / 128; i++) {
        int idx = i * 128 + b;             // idx = f*NQ + j
        int f = idx >> 4, j = idx & 15;
        float2 ri = Qri[(size_t)f * NUM_QUERIES + qbase + j];
        float  m  = Qm [(size_t)f * NUM_QUERIES + qbase + j];
        qlds[idx] = make_float4(ri.x, ri.y, m, 0.0f);
    }
    __syncthreads();

    float acc[NQ];
    #pragma unroll
    for (int j = 0; j < NQ; j++) acc[j] = 0.0f;

    float4 P = probe4[b];                  // f = 0
    #pragma unroll 2
    for (int f = 0; f < NUM_FREQS; f++) {
        int fn = (f + 1 < NUM_FREQS) ? (f + 1) : (NUM_FREQS - 1);
        float4 Pn = probe4[fn * NUM_BINS + b];   // prefetch next f (vmcnt pipe)
        #pragma unroll
        for (int j = 0; j < NQ; j++) {
            float4 qv = qlds[f * NQ + j];        // ds_read_b128 broadcast
            float er = P.x - qv.x;
            float ei = P.y - qv.y;
            float d  = __builtin_amdgcn_sqrtf(fmaf(er, er, fmaf(ei, ei, EPS)));
            acc[j] = fmaf(d, P.z, fmaf(qv.z, P.w, acc[j]));
        }
        P = Pn;
    }

    float bb = bias[b];
    #pragma unroll
    for (int j = 0; j < NQ; j++)
        out[(size_t)(qbase + j) * NUM_BINS + b] = acc[j] + bb;   // coalesced
}

// ---------------------------------------------------------------------------
// Fallback (only if ws_size is too small): fully self-contained, slower.
// ---------------------------------------------------------------------------
__global__ void fallback_kernel(const float* __restrict__ Q,
                                const float* __restrict__ rp,
                                const float* __restrict__ wraw,
                                const float* __restrict__ mw,
                                const float* __restrict__ bias,
                                float* __restrict__ out) {
    __shared__ float qn[HEAD_DIM];
    __shared__ float qmag[NUM_FREQS];
    __shared__ float red[NUM_BINS];
    const int t = threadIdx.x;
    const int q = blockIdx.x;

    float v = Q[(size_t)q * HEAD_DIM + t];
    red[t] = v * v;
    __syncthreads();
    for (int s = 64; s > 0; s >>= 1) {
        if (t < s) red[t] += red[t + s];
        __syncthreads();
    }
    float inv = 1.0f / (__builtin_amdgcn_sqrtf(red[0]) + EPS);
    qn[t] = v * inv;
    __syncthreads();
    if (t < NUM_FREQS) {
        float a = qn[t], c = qn[t + NUM_FREQS];
        qmag[t] = __builtin_amdgcn_sqrtf(fmaf(a, a, fmaf(c, c, EPS)));
    }
    __syncthreads();

    const int b = t;
    float acc = 0.0f;
    for (int f = 0; f < NUM_FREQS; f++) {
        float pr = rp[(size_t)b * HEAD_DIM + f];
        float pi = rp[(size_t)b * HEAD_DIM + NUM_FREQS + f];
        float w  = wraw[(size_t)b * NUM_FREQS + f];
        float ew = -(fmaxf(w, 0.0f) + log1pf(expf(-fabsf(w))));
        float er = pr - qn[f];
        float ei = pi - qn[f + NUM_FREQS];
        float d  = __builtin_amdgcn_sqrtf(fmaf(er, er, fmaf(ei, ei, EPS)));
        acc = fmaf(d, ew, fmaf(qmag[f], mw[(size_t)b * NUM_FREQS + f], acc));
    }
    out[(size_t)q * NUM_BINS + b] = acc + bias[b];
}

// ---------------------------------------------------------------------------
extern "C" void kernel_launch(void* const* d_in, const int* in_sizes, int n_in,
                              void* d_out, int out_size, void* d_ws, size_t ws_size,
                              hipStream_t stream) {
    const float* Q    = (const float*)d_in[0];
    const float* rp   = (const float*)d_in[1];
    const float* wraw = (const float*)d_in[2];
    const float* mw   = (const float*)d_in[3];
    const float* bias = (const float*)d_in[4];
    float* out = (float*)d_out;

    const size_t probeBytes = (size_t)NUM_FREQS * NUM_BINS * sizeof(float4);    // 128 KiB
    const size_t qriBytes   = (size_t)NUM_FREQS * NUM_QUERIES * sizeof(float2); // 16 MiB
    const size_t qmBytes    = (size_t)NUM_FREQS * NUM_QUERIES * sizeof(float);  //  8 MiB
    const size_t need       = probeBytes + qriBytes + qmBytes;                  // 24.1 MiB

    if (ws_size >= need) {
        float4* probe4 = (float4*)d_ws;
        float2* Qri    = (float2*)((char*)d_ws + probeBytes);
        float*  Qm     = (float*)((char*)d_ws + probeBytes + qriBytes);

        hipLaunchKernelGGL(prep_probe, dim3((NUM_FREQS * NUM_BINS + 255) / 256),
                           dim3(256), 0, stream, rp, wraw, mw, probe4);
        hipLaunchKernelGGL(prep_q, dim3(NUM_QUERIES / 256), dim3(256), 0, stream,
                           Q, Qri, Qm);
        hipLaunchKernelGGL(main_kernel, dim3(NUM_QUERIES / NQ), dim3(128), 0,
                           stream, probe4, Qri, Qm, bias, out);
    } else {
        hipLaunchKernelGGL(fallback_kernel, dim3(NUM_QUERIES), dim3(NUM_BINS), 0,
                           stream, Q, rp, wraw, mw, bias, out);
    }
}

// Round 6
// 91.530 us; speedup vs baseline: 1.9714x; 1.0584x over previous
//
#include <hip/hip_runtime.h>
#include <math.h>

#define NUM_FREQS   64
#define NUM_BINS    128
#define NUM_QUERIES 32768
#define HEAD_DIM    128
#define EPS         1e-8f
#define NQB         64   // queries per block (4 waves x 16 j each)

// ---------------------------------------------------------------------------
// Prep 1: pack probe-side constants, transposed to [f][b].
// probe4[f*128+b] = { P_real[b][f], P_imag[b][f], -softplus(w[b][f]), mw[b][f] }
// ---------------------------------------------------------------------------
__global__ void prep_probe(const float* __restrict__ rp,
                           const float* __restrict__ wraw,
                           const float* __restrict__ mw,
                           float4* __restrict__ probe4) {
    int tid = blockIdx.x * blockDim.x + threadIdx.x;   // tid = f*128 + b
    if (tid >= NUM_FREQS * NUM_BINS) return;
    int f = tid >> 7;
    int b = tid & 127;
    float pr = rp[b * HEAD_DIM + f];
    float pi = rp[b * HEAD_DIM + NUM_FREQS + f];
    float w  = wraw[b * NUM_FREQS + f];
    float sp = fmaxf(w, 0.0f) + log1pf(expf(-fabsf(w)));   // stable softplus
    float m  = mw[b * NUM_FREQS + f];
    probe4[tid] = make_float4(pr, pi, -sp, m);
}

// ---------------------------------------------------------------------------
// Prep 2: normalize Q rows; write transposed Qri[f][q] (float2) + Qm[f][q].
// ---------------------------------------------------------------------------
__global__ void prep_q(const float* __restrict__ Q,
                       float2* __restrict__ Qri,
                       float*  __restrict__ Qm) {
    int q = blockIdx.x * blockDim.x + threadIdx.x;
    if (q >= NUM_QUERIES) return;
    const float4* Qrow = reinterpret_cast<const float4*>(Q + (size_t)q * HEAD_DIM);
    float4 buf[32];
    float s = 0.0f;
    #pragma unroll
    for (int i = 0; i < 32; i++) {
        float4 v = Qrow[i];
        buf[i] = v;
        s = fmaf(v.x, v.x, fmaf(v.y, v.y, fmaf(v.z, v.z, fmaf(v.w, v.w, s))));
    }
    float inv = 1.0f / (__builtin_amdgcn_sqrtf(s) + EPS);
    #pragma unroll
    for (int i = 0; i < 16; i++) {
        float4 r  = buf[i];        // dims 4i..4i+3       -> real part
        float4 im = buf[16 + i];   // dims 64+4i..64+4i+3 -> imag part
        float rr[4] = { r.x,  r.y,  r.z,  r.w  };
        float ii[4] = { im.x, im.y, im.z, im.w };
        #pragma unroll
        for (int k = 0; k < 4; k++) {
            float qr = rr[k] * inv;
            float qi = ii[k] * inv;
            float qm = __builtin_amdgcn_sqrtf(fmaf(qr, qr, fmaf(qi, qi, EPS)));
            int f = 4 * i + k;
            Qri[(size_t)f * NUM_QUERIES + q] = make_float2(qr, qi);  // coalesced
            Qm [(size_t)f * NUM_QUERIES + q] = qm;
        }
    }
}

// ---------------------------------------------------------------------------
// Main: block = 256 threads (4 waves). Block owns a 64-query panel; wave w
// owns j-chunk [16w, 16w+16). Each lane covers 2 bins (lane, lane+64).
// LDS panel packed densely: {qr,qi} b128 = 2 j's, qm b128 = 4 j's ->
// 12 broadcast reads/f/wave (144 LDS cy) vs 640 VALU cy -> VALU-bound.
// Probe side: 2 coalesced float4 global loads per f, depth-1 prefetched.
// ---------------------------------------------------------------------------
__global__ __launch_bounds__(256) void main_kernel(
        const float4* __restrict__ probe4,
        const float2* __restrict__ Qri,
        const float*  __restrict__ Qm,
        const float*  __restrict__ bias,
        float*        __restrict__ out) {
    __shared__ float2 qri[NUM_FREQS][NQB];   // 32 KB  [f][j] {qr,qi}
    __shared__ float  qmv[NUM_FREQS][NQB];   // 16 KB  [f][j] qm

    const int tid   = threadIdx.x;
    const int qbase = blockIdx.x * NQB;

    // Stage q-panel (coalesced: consecutive tid -> consecutive j).
    #pragma unroll
    for (int i = 0; i < (NUM_FREQS * NQB) / 256; i++) {
        int idx = i * 256 + tid;             // idx = f*64 + j
        int f = idx >> 6, j = idx & 63;
        qri[f][j] = Qri[(size_t)f * NUM_QUERIES + qbase + j];
        qmv[f][j] = Qm [(size_t)f * NUM_QUERIES + qbase + j];
    }
    __syncthreads();

    const int lane = tid & 63;
    const int wave = tid >> 6;
    const int jb   = wave * 16;              // this wave's j-chunk base

    float acc0[16], acc1[16];
    #pragma unroll
    for (int j = 0; j < 16; j++) { acc0[j] = 0.0f; acc1[j] = 0.0f; }

    float4 P0 = probe4[lane];
    float4 P1 = probe4[64 + lane];
    #pragma unroll 2
    for (int f = 0; f < NUM_FREQS; f++) {
        int fn = (f + 1) & (NUM_FREQS - 1);              // wrap: last prefetch harmless
        float4 P0n = probe4[fn * NUM_BINS + lane];       // vmcnt-pipelined prefetch
        float4 P1n = probe4[fn * NUM_BINS + 64 + lane];

        const float4* aq = reinterpret_cast<const float4*>(&qri[f][jb]);  // 8 reads
        const float4* mq = reinterpret_cast<const float4*>(&qmv[f][jb]);  // 4 reads
        float4 m0 = mq[0], m1 = mq[1], m2 = mq[2], m3 = mq[3];
        float mm[16] = { m0.x, m0.y, m0.z, m0.w,  m1.x, m1.y, m1.z, m1.w,
                         m2.x, m2.y, m2.z, m2.w,  m3.x, m3.y, m3.z, m3.w };

        #pragma unroll
        for (int k = 0; k < 8; k++) {
            float4 a = aq[k];                // {qr(2k), qi(2k), qr(2k+1), qi(2k+1)}
            {   // j = 2k
                float er0 = P0.x - a.x, ei0 = P0.y - a.y;
                float d0  = __builtin_amdgcn_sqrtf(fmaf(er0, er0, fmaf(ei0, ei0, EPS)));
                acc0[2*k] = fmaf(d0, P0.z, fmaf(mm[2*k], P0.w, acc0[2*k]));
                float er1 = P1.x - a.x, ei1 = P1.y - a.y;
                float d1  = __builtin_amdgcn_sqrtf(fmaf(er1, er1, fmaf(ei1, ei1, EPS)));
                acc1[2*k] = fmaf(d1, P1.z, fmaf(mm[2*k], P1.w, acc1[2*k]));
            }
            {   // j = 2k+1
                float er0 = P0.x - a.z, ei0 = P0.y - a.w;
                float d0  = __builtin_amdgcn_sqrtf(fmaf(er0, er0, fmaf(ei0, ei0, EPS)));
                acc0[2*k+1] = fmaf(d0, P0.z, fmaf(mm[2*k+1], P0.w, acc0[2*k+1]));
                float er1 = P1.x - a.z, ei1 = P1.y - a.w;
                float d1  = __builtin_amdgcn_sqrtf(fmaf(er1, er1, fmaf(ei1, ei1, EPS)));
                acc1[2*k+1] = fmaf(d1, P1.z, fmaf(mm[2*k+1], P1.w, acc1[2*k+1]));
            }
        }
        P0 = P0n; P1 = P1n;
    }

    float b0 = bias[lane];
    float b1 = bias[64 + lane];
    #pragma unroll
    for (int j = 0; j < 16; j++) {
        size_t row = (size_t)(qbase + jb + j) * NUM_BINS;
        out[row + lane]      = acc0[j] + b0;     // coalesced
        out[row + 64 + lane] = acc1[j] + b1;     // coalesced
    }
}

// ---------------------------------------------------------------------------
// Fallback (only if ws_size is too small): fully self-contained, slower.
// ---------------------------------------------------------------------------
__global__ void fallback_kernel(const float* __restrict__ Q,
                                const float* __restrict__ rp,
                                const float* __restrict__ wraw,
                                const float* __restrict__ mw,
                                const float* __restrict__ bias,
                                float* __restrict__ out) {
    __shared__ float qn[HEAD_DIM];
    __shared__ float qmag[NUM_FREQS];
    __shared__ float red[NUM_BINS];
    const int t = threadIdx.x;
    const int q = blockIdx.x;

    float v = Q[(size_t)q * HEAD_DIM + t];
    red[t] = v * v;
    __syncthreads();
    for (int s = 64; s > 0; s >>= 1) {
        if (t < s) red[t] += red[t + s];
        __syncthreads();
    }
    float inv = 1.0f / (__builtin_amdgcn_sqrtf(red[0]) + EPS);
    qn[t] = v * inv;
    __syncthreads();
    if (t < NUM_FREQS) {
        float a = qn[t], c = qn[t + NUM_FREQS];
        qmag[t] = __builtin_amdgcn_sqrtf(fmaf(a, a, fmaf(c, c, EPS)));
    }
    __syncthreads();

    const int b = t;
    float acc = 0.0f;
    for (int f = 0; f < NUM_FREQS; f++) {
        float pr = rp[(size_t)b * HEAD_DIM + f];
        float pi = rp[(size_t)b * HEAD_DIM + NUM_FREQS + f];
        float w  = wraw[(size_t)b * NUM_FREQS + f];
        float ew = -(fmaxf(w, 0.0f) + log1pf(expf(-fabsf(w))));
        float er = pr - qn[f];
        float ei = pi - qn[f + NUM_FREQS];
        float d  = __builtin_amdgcn_sqrtf(fmaf(er, er, fmaf(ei, ei, EPS)));
        acc = fmaf(d, ew, fmaf(qmag[f], mw[(size_t)b * NUM_FREQS + f], acc));
    }
    out[(size_t)q * NUM_BINS + b] = acc + bias[b];
}

// ---------------------------------------------------------------------------
extern "C" void kernel_launch(void* const* d_in, const int* in_sizes, int n_in,
                              void* d_out, int out_size, void* d_ws, size_t ws_size,
                              hipStream_t stream) {
    const float* Q    = (const float*)d_in[0];
    const float* rp   = (const float*)d_in[1];
    const float* wraw = (const float*)d_in[2];
    const float* mw   = (const float*)d_in[3];
    const float* bias = (const float*)d_in[4];
    float* out = (float*)d_out;

    const size_t probeBytes = (size_t)NUM_FREQS * NUM_BINS * sizeof(float4);    // 128 KiB
    const size_t qriBytes   = (size_t)NUM_FREQS * NUM_QUERIES * sizeof(float2); // 16 MiB
    const size_t qmBytes    = (size_t)NUM_FREQS * NUM_QUERIES * sizeof(float);  //  8 MiB
    const size_t need       = probeBytes + qriBytes + qmBytes;                  // 24.1 MiB

    if (ws_size >= need) {
        float4* probe4 = (float4*)d_ws;
        float2* Qri    = (float2*)((char*)d_ws + probeBytes);
        float*  Qm     = (float*)((char*)d_ws + probeBytes + qriBytes);

        hipLaunchKernelGGL(prep_probe, dim3((NUM_FREQS * NUM_BINS + 255) / 256),
                           dim3(256), 0, stream, rp, wraw, mw, probe4);
        hipLaunchKernelGGL(prep_q, dim3(NUM_QUERIES / 256), dim3(256), 0, stream,
                           Q, Qri, Qm);
        hipLaunchKernelGGL(main_kernel, dim3(NUM_QUERIES / NQB), dim3(256), 0,
                           stream, probe4, Qri, Qm, bias, out);
    } else {
        hipLaunchKernelGGL(fallback_kernel, dim3(NUM_QUERIES), dim3(NUM_BINS), 0,
                           stream, Q, rp, wraw, mw, bias, out);
    }
}

// Round 7
// 80.863 us; speedup vs baseline: 2.2315x; 1.1319x over previous
//
#include <hip/hip_runtime.h>
#include <math.h>

#define NUM_FREQS   64
#define NUM_BINS    128
#define NUM_QUERIES 32768
#define HEAD_DIM    128
#define EPS         1e-8f
#define NQB         32   // queries per block (4 waves x 8 j each)

// ---------------------------------------------------------------------------
// Prep 1: pack probe-side constants, transposed to [f][b].
// probe4[f*128+b] = { P_real[b][f], P_imag[b][f], -softplus(w[b][f]), mw[b][f] }
// ---------------------------------------------------------------------------
__global__ void prep_probe(const float* __restrict__ rp,
                           const float* __restrict__ wraw,
                           const float* __restrict__ mw,
                           float4* __restrict__ probe4) {
    int tid = blockIdx.x * blockDim.x + threadIdx.x;   // tid = f*128 + b
    if (tid >= NUM_FREQS * NUM_BINS) return;
    int f = tid >> 7;
    int b = tid & 127;
    float pr = rp[b * HEAD_DIM + f];
    float pi = rp[b * HEAD_DIM + NUM_FREQS + f];
    float w  = wraw[b * NUM_FREQS + f];
    float sp = fmaxf(w, 0.0f) + log1pf(expf(-fabsf(w)));   // stable softplus
    float m  = mw[b * NUM_FREQS + f];
    probe4[tid] = make_float4(pr, pi, -sp, m);
}

// ---------------------------------------------------------------------------
// Prep 2: normalize Q rows; write transposed Qri[f][q] (float2) + Qm[f][q].
// ---------------------------------------------------------------------------
__global__ void prep_q(const float* __restrict__ Q,
                       float2* __restrict__ Qri,
                       float*  __restrict__ Qm) {
    int q = blockIdx.x * blockDim.x + threadIdx.x;
    if (q >= NUM_QUERIES) return;
    const float4* Qrow = reinterpret_cast<const float4*>(Q + (size_t)q * HEAD_DIM);
    float4 buf[32];
    float s = 0.0f;
    #pragma unroll
    for (int i = 0; i < 32; i++) {
        float4 v = Qrow[i];
        buf[i] = v;
        s = fmaf(v.x, v.x, fmaf(v.y, v.y, fmaf(v.z, v.z, fmaf(v.w, v.w, s))));
    }
    float inv = 1.0f / (__builtin_amdgcn_sqrtf(s) + EPS);
    #pragma unroll
    for (int i = 0; i < 16; i++) {
        float4 r  = buf[i];        // dims 4i..4i+3       -> real part
        float4 im = buf[16 + i];   // dims 64+4i..64+4i+3 -> imag part
        float rr[4] = { r.x,  r.y,  r.z,  r.w  };
        float ii[4] = { im.x, im.y, im.z, im.w };
        #pragma unroll
        for (int k = 0; k < 4; k++) {
            float qr = rr[k] * inv;
            float qi = ii[k] * inv;
            float qm = __builtin_amdgcn_sqrtf(fmaf(qr, qr, fmaf(qi, qi, EPS)));
            int f = 4 * i + k;
            Qri[(size_t)f * NUM_QUERIES + q] = make_float2(qr, qi);  // coalesced
            Qm [(size_t)f * NUM_QUERIES + q] = qm;
        }
    }
}

// ---------------------------------------------------------------------------
// Main: block = 256 threads (4 waves). Block owns a 32-query panel; wave w
// owns j-chunk [8w, 8w+8). Each lane covers 2 bins (lane, lane+64).
// Grid = 1024 blocks = 4 blocks/CU ALL CO-RESIDENT (24 KB LDS each) ->
// 4 waves/SIMD of TLP to overlap the LDS and VALU pipes.
// Per wave-f: 6 broadcast b128 reads (72 LDS cy) vs 320 VALU cy.
// Probe side: 2 coalesced float4 global loads per f, depth-1 prefetched.
// ---------------------------------------------------------------------------
__global__ __launch_bounds__(256) void main_kernel(
        const float4* __restrict__ probe4,
        const float2* __restrict__ Qri,
        const float*  __restrict__ Qm,
        const float*  __restrict__ bias,
        float*        __restrict__ out) {
    __shared__ float2 qri[NUM_FREQS][NQB];   // 16 KB  [f][j] {qr,qi}
    __shared__ float  qmv[NUM_FREQS][NQB];   // 8 KB   [f][j] qm

    const int tid   = threadIdx.x;
    const int qbase = blockIdx.x * NQB;

    // Stage q-panel (coalesced: consecutive tid -> consecutive j).
    #pragma unroll
    for (int i = 0; i < (NUM_FREQS * NQB) / 256; i++) {
        int idx = i * 256 + tid;             // idx = f*32 + j
        int f = idx >> 5, j = idx & 31;
        qri[f][j] = Qri[(size_t)f * NUM_QUERIES + qbase + j];
        qmv[f][j] = Qm [(size_t)f * NUM_QUERIES + qbase + j];
    }
    __syncthreads();

    const int lane = tid & 63;
    const int wave = tid >> 6;
    const int jb   = wave * 8;               // this wave's j-chunk base

    float acc0[8], acc1[8];
    #pragma unroll
    for (int j = 0; j < 8; j++) { acc0[j] = 0.0f; acc1[j] = 0.0f; }

    float4 P0 = probe4[lane];
    float4 P1 = probe4[64 + lane];
    #pragma unroll 2
    for (int f = 0; f < NUM_FREQS; f++) {
        int fn = (f + 1) & (NUM_FREQS - 1);              // wrap: last prefetch harmless
        float4 P0n = probe4[fn * NUM_BINS + lane];       // vmcnt-pipelined prefetch
        float4 P1n = probe4[fn * NUM_BINS + 64 + lane];

        const float4* aq = reinterpret_cast<const float4*>(&qri[f][jb]);  // 4 reads
        const float4* mq = reinterpret_cast<const float4*>(&qmv[f][jb]);  // 2 reads
        float4 m0 = mq[0], m1 = mq[1];
        float mm[8] = { m0.x, m0.y, m0.z, m0.w,  m1.x, m1.y, m1.z, m1.w };

        #pragma unroll
        for (int k = 0; k < 4; k++) {
            float4 a = aq[k];                // {qr(2k), qi(2k), qr(2k+1), qi(2k+1)}
            {   // j = 2k
                float er0 = P0.x - a.x, ei0 = P0.y - a.y;
                float d0  = __builtin_amdgcn_sqrtf(fmaf(er0, er0, fmaf(ei0, ei0, EPS)));
                acc0[2*k] = fmaf(d0, P0.z, fmaf(mm[2*k], P0.w, acc0[2*k]));
                float er1 = P1.x - a.x, ei1 = P1.y - a.y;
                float d1  = __builtin_amdgcn_sqrtf(fmaf(er1, er1, fmaf(ei1, ei1, EPS)));
                acc1[2*k] = fmaf(d1, P1.z, fmaf(mm[2*k], P1.w, acc1[2*k]));
            }
            {   // j = 2k+1
                float er0 = P0.x - a.z, ei0 = P0.y - a.w;
                float d0  = __builtin_amdgcn_sqrtf(fmaf(er0, er0, fmaf(ei0, ei0, EPS)));
                acc0[2*k+1] = fmaf(d0, P0.z, fmaf(mm[2*k+1], P0.w, acc0[2*k+1]));
                float er1 = P1.x - a.z, ei1 = P1.y - a.w;
                float d1  = __builtin_amdgcn_sqrtf(fmaf(er1, er1, fmaf(ei1, ei1, EPS)));
                acc1[2*k+1] = fmaf(d1, P1.z, fmaf(mm[2*k+1], P1.w, acc1[2*k+1]));
            }
        }
        P0 = P0n; P1 = P1n;
    }

    float b0 = bias[lane];
    float b1 = bias[64 + lane];
    #pragma unroll
    for (int j = 0; j < 8; j++) {
        size_t row = (size_t)(qbase + jb + j) * NUM_BINS;
        out[row + lane]      = acc0[j] + b0;     // coalesced
        out[row + 64 + lane] = acc1[j] + b1;     // coalesced
    }
}

// ---------------------------------------------------------------------------
// Fallback (only if ws_size is too small): fully self-contained, slower.
// ---------------------------------------------------------------------------
__global__ void fallback_kernel(const float* __restrict__ Q,
                                const float* __restrict__ rp,
                                const float* __restrict__ wraw,
                                const float* __restrict__ mw,
                                const float* __restrict__ bias,
                                float* __restrict__ out) {
    __shared__ float qn[HEAD_DIM];
    __shared__ float qmag[NUM_FREQS];
    __shared__ float red[NUM_BINS];
    const int t = threadIdx.x;
    const int q = blockIdx.x;

    float v = Q[(size_t)q * HEAD_DIM + t];
    red[t] = v * v;
    __syncthreads();
    for (int s = 64; s > 0; s >>= 1) {
        if (t < s) red[t] += red[t + s];
        __syncthreads();
    }
    float inv = 1.0f / (__builtin_amdgcn_sqrtf(red[0]) + EPS);
    qn[t] = v * inv;
    __syncthreads();
    if (t < NUM_FREQS) {
        float a = qn[t], c = qn[t + NUM_FREQS];
        qmag[t] = __builtin_amdgcn_sqrtf(fmaf(a, a, fmaf(c, c, EPS)));
    }
    __syncthreads();

    const int b = t;
    float acc = 0.0f;
    for (int f = 0; f < NUM_FREQS; f++) {
        float pr = rp[(size_t)b * HEAD_DIM + f];
        float pi = rp[(size_t)b * HEAD_DIM + NUM_FREQS + f];
        float w  = wraw[(size_t)b * NUM_FREQS + f];
        float ew = -(fmaxf(w, 0.0f) + log1pf(expf(-fabsf(w))));
        float er = pr - qn[f];
        float ei = pi - qn[f + NUM_FREQS];
        float d  = __builtin_amdgcn_sqrtf(fmaf(er, er, fmaf(ei, ei, EPS)));
        acc = fmaf(d, ew, fmaf(qmag[f], mw[(size_t)b * NUM_FREQS + f], acc));
    }
    out[(size_t)q * NUM_BINS + b] = acc + bias[b];
}

// ---------------------------------------------------------------------------
extern "C" void kernel_launch(void* const* d_in, const int* in_sizes, int n_in,
                              void* d_out, int out_size, void* d_ws, size_t ws_size,
                              hipStream_t stream) {
    const float* Q    = (const float*)d_in[0];
    const float* rp   = (const float*)d_in[1];
    const float* wraw = (const float*)d_in[2];
    const float* mw   = (const float*)d_in[3];
    const float* bias = (const float*)d_in[4];
    float* out = (float*)d_out;

    const size_t probeBytes = (size_t)NUM_FREQS * NUM_BINS * sizeof(float4);    // 128 KiB
    const size_t qriBytes   = (size_t)NUM_FREQS * NUM_QUERIES * sizeof(float2); // 16 MiB
    const size_t qmBytes    = (size_t)NUM_FREQS * NUM_QUERIES * sizeof(float);  //  8 MiB
    const size_t need       = probeBytes + qriBytes + qmBytes;                  // 24.1 MiB

    if (ws_size >= need) {
        float4* probe4 = (float4*)d_ws;
        float2* Qri    = (float2*)((char*)d_ws + probeBytes);
        float*  Qm     = (float*)((char*)d_ws + probeBytes + qriBytes);

        hipLaunchKernelGGL(prep_probe, dim3((NUM_FREQS * NUM_BINS + 255) / 256),
                           dim3(256), 0, stream, rp, wraw, mw, probe4);
        hipLaunchKernelGGL(prep_q, dim3(NUM_QUERIES / 256), dim3(256), 0, stream,
                           Q, Qri, Qm);
        hipLaunchKernelGGL(main_kernel, dim3(NUM_QUERIES / NQB), dim3(256), 0,
                           stream, probe4, Qri, Qm, bias, out);
    } else {
        hipLaunchKernelGGL(fallback_kernel, dim3(NUM_QUERIES), dim3(NUM_BINS), 0,
                           stream, Q, rp, wraw, mw, bias, out);
    }
}

// Round 8
// 74.735 us; speedup vs baseline: 2.4145x; 1.0820x over previous
//
#include <hip/hip_runtime.h>
#include <math.h>

#define NUM_FREQS   64
#define NUM_BINS    128
#define NUM_QUERIES 32768
#define HEAD_DIM    128
#define EPS         1e-8f
#define NQB         32   // queries per block (4 waves x 8 j each)

// ---------------------------------------------------------------------------
// Fused prep: blocks [0,128) normalize Q and write transposed Qri/Qm;
// blocks [128,160) pack probe-side constants transposed to [f][b].
// ---------------------------------------------------------------------------
__global__ void prep_fused(const float* __restrict__ Q,
                           const float* __restrict__ rp,
                           const float* __restrict__ wraw,
                           const float* __restrict__ mw,
                           float2* __restrict__ Qri,
                           float*  __restrict__ Qm,
                           float4* __restrict__ probe4) {
    const int bid = blockIdx.x;
    const int tid = threadIdx.x;
    if (bid < 128) {
        // ---- prep_q ----
        int q = bid * 256 + tid;
        const float4* Qrow = reinterpret_cast<const float4*>(Q + (size_t)q * HEAD_DIM);
        float4 buf[32];
        float s = 0.0f;
        #pragma unroll
        for (int i = 0; i < 32; i++) {
            float4 v = Qrow[i];
            buf[i] = v;
            s = fmaf(v.x, v.x, fmaf(v.y, v.y, fmaf(v.z, v.z, fmaf(v.w, v.w, s))));
        }
        float inv = 1.0f / (__builtin_amdgcn_sqrtf(s) + EPS);
        #pragma unroll
        for (int i = 0; i < 16; i++) {
            float4 r  = buf[i];        // dims 4i..4i+3       -> real part
            float4 im = buf[16 + i];   // dims 64+4i..64+4i+3 -> imag part
            float rr[4] = { r.x,  r.y,  r.z,  r.w  };
            float ii[4] = { im.x, im.y, im.z, im.w };
            #pragma unroll
            for (int k = 0; k < 4; k++) {
                float qr = rr[k] * inv;
                float qi = ii[k] * inv;
                float qm = __builtin_amdgcn_sqrtf(fmaf(qr, qr, fmaf(qi, qi, EPS)));
                int f = 4 * i + k;
                Qri[(size_t)f * NUM_QUERIES + q] = make_float2(qr, qi);  // coalesced
                Qm [(size_t)f * NUM_QUERIES + q] = qm;
            }
        }
    } else {
        // ---- prep_probe ----
        int idx = (bid - 128) * 256 + tid;       // idx = f*128 + b
        if (idx >= NUM_FREQS * NUM_BINS) return;
        int f = idx >> 7;
        int b = idx & 127;
        float pr = rp[b * HEAD_DIM + f];
        float pi = rp[b * HEAD_DIM + NUM_FREQS + f];
        float w  = wraw[b * NUM_FREQS + f];
        float sp = fmaxf(w, 0.0f) + log1pf(expf(-fabsf(w)));   // stable softplus
        float m  = mw[b * NUM_FREQS + f];
        probe4[idx] = make_float4(pr, pi, -sp, m);
    }
}

// ---------------------------------------------------------------------------
// Main: block = 256 threads (4 waves). Block owns a 32-query panel; wave w
// owns j-chunk [8w, 8w+8). Each lane covers 2 bins (lane, lane+64).
// Grid = 1024 blocks = 4 blocks/CU co-resident (25 KB LDS each).
// Register double-buffer: q-panel regs (a[4], m[2]) and probe regs (P0,P1)
// for f+1 are loaded before computing f -> loop-carried waits span a full
// 448-cycle body, hiding both LDS-queue and L1/L2 latency.
// ---------------------------------------------------------------------------
__global__ __launch_bounds__(256, 4) void main_kernel(
        const float4* __restrict__ probe4,
        const float2* __restrict__ Qri,
        const float*  __restrict__ Qm,
        const float*  __restrict__ bias,
        float*        __restrict__ out) {
    __shared__ float2 qri[NUM_FREQS + 1][NQB];   // +1 guard row for prefetch
    __shared__ float  qmv[NUM_FREQS + 1][NQB];

    const int tid   = threadIdx.x;
    const int qbase = blockIdx.x * NQB;

    // Stage q-panel (coalesced: consecutive tid -> consecutive j).
    #pragma unroll
    for (int i = 0; i < (NUM_FREQS * NQB) / 256; i++) {
        int idx = i * 256 + tid;             // idx = f*32 + j
        int f = idx >> 5, j = idx & 31;
        qri[f][j] = Qri[(size_t)f * NUM_QUERIES + qbase + j];
        qmv[f][j] = Qm [(size_t)f * NUM_QUERIES + qbase + j];
    }
    __syncthreads();

    const int lane = tid & 63;
    const int wave = tid >> 6;
    const int jb   = wave * 8;               // this wave's j-chunk base

    float acc0[8], acc1[8];
    #pragma unroll
    for (int j = 0; j < 8; j++) { acc0[j] = 0.0f; acc1[j] = 0.0f; }

    // Walking pointers (one add per f each; second bin via constant offset).
    const float4* pp = probe4 + lane;                                  // f row
    const float4* aq = reinterpret_cast<const float4*>(&qri[0][jb]);   // 16 f4 / row
    const float4* mq = reinterpret_cast<const float4*>(&qmv[0][jb]);   //  8 f4 / row

    float4 P0 = pp[0], P1 = pp[64];
    float4 a0 = aq[0], a1 = aq[1], a2 = aq[2], a3 = aq[3];
    float4 m0 = mq[0], m1 = mq[1];

    #pragma unroll 4
    for (int f = 0; f < NUM_FREQS; f++) {
        // ---- prefetch f+1 into the shadow registers ----
        const float4* ppn = pp + NUM_BINS;
        float4 P0n = ppn[0],  P1n = ppn[64];
        const float4* aqn = aq + 16;
        const float4* mqn = mq + 8;
        float4 a0n = aqn[0], a1n = aqn[1], a2n = aqn[2], a3n = aqn[3];
        float4 m0n = mqn[0], m1n = mqn[1];

        // ---- compute f ----
        const float mmv[8] = { m0.x, m0.y, m0.z, m0.w,  m1.x, m1.y, m1.z, m1.w };
        const float4 av[4] = { a0, a1, a2, a3 };
        #pragma unroll
        for (int k = 0; k < 4; k++) {
            float4 a = av[k];                // {qr(2k), qi(2k), qr(2k+1), qi(2k+1)}
            {   // j = 2k
                float er0 = P0.x - a.x, ei0 = P0.y - a.y;
                float d0  = __builtin_amdgcn_sqrtf(fmaf(er0, er0, fmaf(ei0, ei0, EPS)));
                acc0[2*k] = fmaf(d0, P0.z, fmaf(mmv[2*k], P0.w, acc0[2*k]));
                float er1 = P1.x - a.x, ei1 = P1.y - a.y;
                float d1  = __builtin_amdgcn_sqrtf(fmaf(er1, er1, fmaf(ei1, ei1, EPS)));
                acc1[2*k] = fmaf(d1, P1.z, fmaf(mmv[2*k], P1.w, acc1[2*k]));
            }
            {   // j = 2k+1
                float er0 = P0.x - a.z, ei0 = P0.y - a.w;
                float d0  = __builtin_amdgcn_sqrtf(fmaf(er0, er0, fmaf(ei0, ei0, EPS)));
                acc0[2*k+1] = fmaf(d0, P0.z, fmaf(mmv[2*k+1], P0.w, acc0[2*k+1]));
                float er1 = P1.x - a.z, ei1 = P1.y - a.w;
                float d1  = __builtin_amdgcn_sqrtf(fmaf(er1, er1, fmaf(ei1, ei1, EPS)));
                acc1[2*k+1] = fmaf(d1, P1.z, fmaf(mmv[2*k+1], P1.w, acc1[2*k+1]));
            }
        }

        // ---- rotate shadow -> live (register renaming under unroll) ----
        P0 = P0n; P1 = P1n;
        a0 = a0n; a1 = a1n; a2 = a2n; a3 = a3n;
        m0 = m0n; m1 = m1n;
        pp = ppn; aq = aqn; mq = mqn;
    }

    float b0 = bias[lane];
    float b1 = bias[64 + lane];
    #pragma unroll
    for (int j = 0; j < 8; j++) {
        size_t row = (size_t)(qbase + jb + j) * NUM_BINS;
        out[row + lane]      = acc0[j] + b0;     // coalesced
        out[row + 64 + lane] = acc1[j] + b1;     // coalesced
    }
}

// ---------------------------------------------------------------------------
// Fallback (only if ws_size is too small): fully self-contained, slower.
// ---------------------------------------------------------------------------
__global__ void fallback_kernel(const float* __restrict__ Q,
                                const float* __restrict__ rp,
                                const float* __restrict__ wraw,
                                const float* __restrict__ mw,
                                const float* __restrict__ bias,
                                float* __restrict__ out) {
    __shared__ float qn[HEAD_DIM];
    __shared__ float qmag[NUM_FREQS];
    __shared__ float red[NUM_BINS];
    const int t = threadIdx.x;
    const int q = blockIdx.x;

    float v = Q[(size_t)q * HEAD_DIM + t];
    red[t] = v * v;
    __syncthreads();
    for (int s = 64; s > 0; s >>= 1) {
        if (t < s) red[t] += red[t + s];
        __syncthreads();
    }
    float inv = 1.0f / (__builtin_amdgcn_sqrtf(red[0]) + EPS);
    qn[t] = v * inv;
    __syncthreads();
    if (t < NUM_FREQS) {
        float a = qn[t], c = qn[t + NUM_FREQS];
        qmag[t] = __builtin_amdgcn_sqrtf(fmaf(a, a, fmaf(c, c, EPS)));
    }
    __syncthreads();

    const int b = t;
    float acc = 0.0f;
    for (int f = 0; f < NUM_FREQS; f++) {
        float pr = rp[(size_t)b * HEAD_DIM + f];
        float pi = rp[(size_t)b * HEAD_DIM + NUM_FREQS + f];
        float w  = wraw[(size_t)b * NUM_FREQS + f];
        float ew = -(fmaxf(w, 0.0f) + log1pf(expf(-fabsf(w))));
        float er = pr - qn[f];
        float ei = pi - qn[f + NUM_FREQS];
        float d  = __builtin_amdgcn_sqrtf(fmaf(er, er, fmaf(ei, ei, EPS)));
        acc = fmaf(d, ew, fmaf(qmag[f], mw[(size_t)b * NUM_FREQS + f], acc));
    }
    out[(size_t)q * NUM_BINS + b] = acc + bias[b];
}

// ---------------------------------------------------------------------------
extern "C" void kernel_launch(void* const* d_in, const int* in_sizes, int n_in,
                              void* d_out, int out_size, void* d_ws, size_t ws_size,
                              hipStream_t stream) {
    const float* Q    = (const float*)d_in[0];
    const float* rp   = (const float*)d_in[1];
    const float* wraw = (const float*)d_in[2];
    const float* mw   = (const float*)d_in[3];
    const float* bias = (const float*)d_in[4];
    float* out = (float*)d_out;

    const size_t probeBytes = (size_t)NUM_FREQS * NUM_BINS * sizeof(float4);    // 128 KiB
    const size_t qriBytes   = (size_t)NUM_FREQS * NUM_QUERIES * sizeof(float2); // 16 MiB
    const size_t qmBytes    = (size_t)NUM_FREQS * NUM_QUERIES * sizeof(float);  //  8 MiB
    const size_t need       = probeBytes + qriBytes + qmBytes;                  // 24.1 MiB

    if (ws_size >= need) {
        float4* probe4 = (float4*)d_ws;
        float2* Qri    = (float2*)((char*)d_ws + probeBytes);
        float*  Qm     = (float*)((char*)d_ws + probeBytes + qriBytes);

        hipLaunchKernelGGL(prep_fused, dim3(128 + 32), dim3(256), 0, stream,
                           Q, rp, wraw, mw, Qri, Qm, probe4);
        hipLaunchKernelGGL(main_kernel, dim3(NUM_QUERIES / NQB), dim3(256), 0,
                           stream, probe4, Qri, Qm, bias, out);
    } else {
        hipLaunchKernelGGL(fallback_kernel, dim3(NUM_QUERIES), dim3(NUM_BINS), 0,
                           stream, Q, rp, wraw, mw, bias, out);
    }
}